// Round 5
// baseline (280.856 us; speedup 1.0000x reference)
//
#include <hip/hip_runtime.h>

typedef __attribute__((ext_vector_type(8))) short short8;
typedef __attribute__((ext_vector_type(4))) float float4v;
typedef __attribute__((ext_vector_type(16))) float float16v;
typedef __attribute__((ext_vector_type(4))) unsigned short ushort4v;

#define NB 32
#define NC 512
#define NL 512
#define NH 8
#define NDK 64

__device__ __forceinline__ unsigned short f2b(float f) {
  union { float f; unsigned int u; } v; v.f = f;
  unsigned int r = v.u + 0x7FFFu + ((v.u >> 16) & 1u);
  return (unsigned short)(r >> 16);
}

__device__ __forceinline__ void gld16(const void* g, void* l) {
  __builtin_amdgcn_global_load_lds(
      (const __attribute__((address_space(1))) unsigned int*)g,
      (__attribute__((address_space(3))) unsigned int*)l, 16, 0, 0);
}

__device__ __forceinline__ float4v bmfma(short8 a, short8 b, float4v c) {
  return __builtin_amdgcn_mfma_f32_16x16x32_bf16(a, b, c, 0, 0, 0);
}

// ---- fp32 -> bf16 weight conversion, 4 matrices in one launch --------------
__global__ __launch_bounds__(256) void cvt4_kernel(
    const float* __restrict__ a, const float* __restrict__ b,
    const float* __restrict__ c, const float* __restrict__ d,
    unsigned short* __restrict__ oa, unsigned short* __restrict__ ob,
    unsigned short* __restrict__ oc, unsigned short* __restrict__ od) {
  int m = blockIdx.y;
  const float* src = (m == 0) ? a : (m == 1) ? b : (m == 2) ? c : d;
  unsigned short* dst = (m == 0) ? oa : (m == 1) ? ob : (m == 2) ? oc : od;
  int i = (blockIdx.x * 256 + threadIdx.x) * 4;
  float4v v = *(const float4v*)(src + i);
  ushort4v o;
  o.x = f2b(v.x); o.y = f2b(v.y); o.z = f2b(v.z); o.w = f2b(v.w);
  *(ushort4v*)(dst + i) = o;
}

// ---- posconv: conv(pos, dw_w) + dw_b, batch-independent; out (L,C) fp32 ----
__global__ __launch_bounds__(256) void posconv_kernel(
    const float* __restrict__ pos,
    const float* __restrict__ qw, const float* __restrict__ qb,
    const float* __restrict__ kw, const float* __restrict__ kb,
    float* __restrict__ pq, float* __restrict__ pk) {
  int t = blockIdx.y, l = blockIdx.x;
  const float* w  = t ? kw : qw;
  const float* bb = t ? kb : qb;
  float* outp = t ? pk : pq;
  for (int c = threadIdx.x; c < NC; c += 256) {
    float acc = bb[c];
#pragma unroll
    for (int tt = 0; tt < 7; ++tt) {
      int ll = l + tt - 3;
      if (ll >= 0 && ll < NL) acc += pos[(size_t)ll * NC + c] * w[c * 7 + tt];
    }
    outp[(size_t)l * NC + c] = acc;
  }
}

// ---- depthwise conv(7); posconv(+bias) added for q,k; writes yT (B,L,C) ----
// Round-4 profile: HBM 37%, VALU 24%, occ 59% -> nothing saturated = convoy/
// latency-bound (loads and compute alternate at each block barrier with zero
// memory in flight during compute). Fix: 4 l-tiles per block with register-
// staged prefetch -- tile t+1's 5 float4 loads are issued BEFORE tile t's
// compute and ds_written after the post-compute barrier, so HBM latency hides
// under conv+stores. Inter-tile halo (16 cols) becomes an L1/L2 hit.
// LDS stays 64 x 84 floats (stride == 20 mod 32: 16-lane b128 read groups
// 2-way = free). Halo 8+8 -> every staged float4 all-in or all-out of range.
#define DW_ISSUE(L0T, R)                                                   \
  {                                                                        \
    _Pragma("unroll")                                                      \
    for (int it = 0; it < 5; ++it) {                                       \
      float4v vv = {0.f, 0.f, 0.f, 0.f};                                   \
      int l = (L0T) + f4l[it];                                             \
      if ((unsigned)l < (unsigned)NL)                                      \
        vv = *(const float4v*)(xrow[it] + (L0T));                          \
      R[it] = vv;                                                          \
    }                                                                      \
  }

#define DW_WRITE(R)                                                        \
  {                                                                        \
    _Pragma("unroll")                                                      \
    for (int it = 0; it < 5; ++it)                                         \
      *(float4v*)(xs + rowi[it] * 84 + (f4l[it] + 8)) = R[it];             \
  }

#define DW_TILE(L0T)                                                       \
  {                                                                        \
    float av[16];                                                          \
    if (t < 2) {                                                           \
      _Pragma("unroll")                                                    \
      for (int i = 0; i < 16; ++i)                                         \
        av[i] = pcv[(size_t)((L0T) + llb + i) * NC + c];                   \
    } else {                                                               \
      _Pragma("unroll")                                                    \
      for (int i = 0; i < 16; ++i) av[i] = bvb;                            \
    }                                                                      \
    __syncthreads();                                                       \
    float w[24];                                                           \
    const float4v* xr = (const float4v*)(xs + cl * 84 + llb + 4);          \
    _Pragma("unroll")                                                      \
    for (int j = 0; j < 6; ++j) {                                          \
      float4v t4 = xr[j];                                                  \
      w[4 * j] = t4.x; w[4 * j + 1] = t4.y;                                \
      w[4 * j + 2] = t4.z; w[4 * j + 3] = t4.w;                            \
    }                                                                      \
    _Pragma("unroll")                                                      \
    for (int i = 0; i < 16; ++i) {                                         \
      float acc = av[i];                                                   \
      _Pragma("unroll")                                                    \
      for (int kk = 0; kk < 7; ++kk) acc += w[i + 1 + kk] * wt[kk];        \
      yT[((size_t)b * NL + (L0T) + llb + i) * NC + c] = f2b(acc);          \
    }                                                                      \
  }

__global__ __launch_bounds__(256) void dw_kernel(
    const float* __restrict__ q, const float* __restrict__ k, const float* __restrict__ v,
    const float* __restrict__ pq, const float* __restrict__ pk,
    const float* __restrict__ qw, const float* __restrict__ kw, const float* __restrict__ vw,
    const float* __restrict__ vb,
    unsigned short* __restrict__ yq, unsigned short* __restrict__ yk,
    unsigned short* __restrict__ yv) {
  int z = blockIdx.z;
  int t = z >> 5, b = z & 31;
  const float* x   = (t == 0) ? q  : (t == 1) ? k  : v;
  const float* dww = (t == 0) ? qw : (t == 1) ? kw : vw;
  const float* pcv = (t == 0) ? pq : pk;  // only used when t<2
  unsigned short* yT = (t == 0) ? yq : (t == 1) ? yk : yv;
  int c0 = blockIdx.y * 64, l0b = blockIdx.x * 256;
  int tid = threadIdx.x;
  __shared__ __attribute__((aligned(16))) float xs[64 * 84];
  int rowi[5], f4l[5];
  const float* xrow[5];
#pragma unroll
  for (int it = 0; it < 5; ++it) {
    int idx = tid + 256 * it;
    int row = idx / 20, f4 = idx - row * 20;
    rowi[it] = row;
    f4l[it] = f4 * 4 - 8;
    xrow[it] = x + ((size_t)b * NC + c0 + row) * NL + f4 * 4 - 8;
  }
  int cl = tid & 63;
  int llb = (tid >> 6) * 16;
  int c = c0 + cl;
  float wt[7];
#pragma unroll
  for (int kk = 0; kk < 7; ++kk) wt[kk] = dww[c * 7 + kk];
  float bvb = (t < 2) ? 0.f : vb[c];

  float4v r[5];
  // prologue: tile 0 loads
  DW_ISSUE(l0b + 0, r);
  DW_WRITE(r);
  DW_ISSUE(l0b + 64, r);   // prefetch tile 1 during tile 0 compute
  DW_TILE(l0b + 0);        // av loads + barrier + conv + stores
  __syncthreads();
  DW_WRITE(r);
  DW_ISSUE(l0b + 128, r);
  DW_TILE(l0b + 64);
  __syncthreads();
  DW_WRITE(r);
  DW_ISSUE(l0b + 192, r);
  DW_TILE(l0b + 128);
  __syncthreads();
  DW_WRITE(r);
  DW_TILE(l0b + 192);
}

// ---- 128x128 MFMA GEMM core, BK=64, global-XOR-swizzled staging ------------
__device__ __forceinline__ void gemm_core_bk64(
    const unsigned short* __restrict__ A, const unsigned short* __restrict__ B,
    unsigned short* lA, unsigned short* lB, float4v acc[4][4], int m0, int n0) {
  int tid = threadIdx.x;
  int lane = tid & 63, quad = lane >> 4, l15 = lane & 15;
  int wave = tid >> 6, wr = wave >> 1, wc = wave & 1;
  const unsigned short* gA[4];
  const unsigned short* gB[4];
  unsigned short* dA[4];
  unsigned short* dB[4];
#pragma unroll
  for (int i = 0; i < 4; ++i) {
    int cc = tid + 256 * i;
    int row = cc >> 3;
    int gc = (cc & 7) ^ (row & 7);
    gA[i] = A + (size_t)(m0 + row) * 512 + gc * 8;
    gB[i] = B + (size_t)(n0 + row) * 512 + gc * 8;
    dA[i] = lA + cc * 8;
    dB[i] = lB + cc * 8;
  }
  for (int k0 = 0; k0 < 512; k0 += 64) {
#pragma unroll
    for (int i = 0; i < 4; ++i) gld16(gA[i] + k0, dA[i]);
#pragma unroll
    for (int i = 0; i < 4; ++i) gld16(gB[i] + k0, dB[i]);
    __syncthreads();
#pragma unroll
    for (int ks = 0; ks < 2; ++ks) {
      int sw = (ks * 4 + quad) ^ (l15 & 7);
      short8 af[4], bf[4];
#pragma unroll
      for (int mt = 0; mt < 4; ++mt)
        af[mt] = *(const short8*)(lA + (wr * 64 + mt * 16 + l15) * 64 + sw * 8);
#pragma unroll
      for (int nt = 0; nt < 4; ++nt)
        bf[nt] = *(const short8*)(lB + (wc * 64 + nt * 16 + l15) * 64 + sw * 8);
#pragma unroll
      for (int mt = 0; mt < 4; ++mt)
#pragma unroll
        for (int nt = 0; nt < 4; ++nt)
          acc[mt][nt] = bmfma(af[mt], bf[nt], acc[mt][nt]);
    }
    __syncthreads();
  }
}

// ---- fused pointwise GEMMs for q,k,v ---------------------------------------
// q output is pre-scaled by 0.125*log2(e) so attention can use exp2 directly.
// Epilogue uses scalar LDS writes (short live ranges -> ~108 VGPR, 4 blocks/CU)
// with XOR-swizzled m-index (bits 3-5 ^= nloc&7) to kill the 16-way conflict.
__global__ __launch_bounds__(256) void pw_gemm_kernel(
    const unsigned short* __restrict__ wqm, const unsigned short* __restrict__ wkm,
    const unsigned short* __restrict__ wvm,
    const unsigned short* __restrict__ yq, const unsigned short* __restrict__ yk,
    const unsigned short* __restrict__ yv,
    const float* __restrict__ qb, const float* __restrict__ kb, const float* __restrict__ vb,
    unsigned short* __restrict__ qT, unsigned short* __restrict__ kT,
    unsigned short* __restrict__ vvo) {
  int z = blockIdx.z, t = z >> 5, b = z & 31;
  const unsigned short* W = (t == 0) ? wqm : (t == 1) ? wkm : wvm;
  const unsigned short* Y = ((t == 0) ? yq : (t == 1) ? yk : yv) + (size_t)b * NL * NC;
  const float* bias = (t == 0) ? qb : (t == 1) ? kb : vb;
  unsigned short* out = (t == 0) ? qT : (t == 1) ? kT : vvo;
  float oscale = (t == 0) ? 0.18033688011112042f : 1.0f;  // 0.125*log2(e) folded into q
  __shared__ __attribute__((aligned(16))) unsigned short buf[16384];
  unsigned short* lA = buf;
  unsigned short* lB = buf + 8192;
  int m0 = blockIdx.y * 128, n0 = blockIdx.x * 128;
  float4v acc[4][4];
#pragma unroll
  for (int i = 0; i < 4; ++i)
#pragma unroll
    for (int j = 0; j < 4; ++j) acc[i][j] = (float4v){0.f, 0.f, 0.f, 0.f};
  gemm_core_bk64(W, Y, lA, lB, acc, m0, n0);
  int tid = threadIdx.x;
  int lane = tid & 63, quad = lane >> 4, l15 = lane & 15;
  int wave = tid >> 6, wr = wave >> 1, wc = wave & 1;
  if (t < 2) {
    // transpose epilogue through LDS: scalar writes, XOR-swizzled m-index;
    // read side inverts with dc ^ (l&7).
#pragma unroll
    for (int mt = 0; mt < 4; ++mt) {
      int mloc = wr * 64 + mt * 16 + quad * 4;
#pragma unroll
      for (int nt = 0; nt < 4; ++nt) {
        int nloc = wc * 64 + nt * 16 + l15;
        int sx = (nloc & 7) << 3;
#pragma unroll
        for (int r = 0; r < 4; ++r) {
          int ml = mloc + r;
          buf[(ml >> 6) * 8192 + nloc * 64 + ((ml & 63) ^ sx)] =
              f2b((acc[mt][nt][r] + bias[m0 + ml]) * oscale);
        }
      }
    }
    __syncthreads();
#pragma unroll
    for (int it = 0; it < 8; ++it) {
      int cc = tid + it * 256;
      int hloc = cc >> 10, l = (cc >> 3) & 127, dc = cc & 7;
      short8 vd = *(const short8*)(buf + hloc * 8192 + l * 64 + ((dc ^ (l & 7)) << 3));
      *(short8*)(out + (((size_t)b * NH + (m0 >> 6) + hloc) * NL + n0 + l) * NDK + dc * 8) = vd;
    }
  } else {
#pragma unroll
    for (int mt = 0; mt < 4; ++mt)
#pragma unroll
      for (int nt = 0; nt < 4; ++nt) {
        int n = n0 + wc * 64 + nt * 16 + l15;
#pragma unroll
        for (int r = 0; r < 4; ++r) {
          int m = m0 + wr * 64 + mt * 16 + quad * 4 + r;
          out[((size_t)b * NC + m) * NL + n] = f2b(acc[mt][nt][r] + bias[m]);
        }
      }
  }
}

// ---- persistent attention, i-outer / j-inner: full K,V resident in LDS -----
// One block per (b,h). K (512x64) + V (64x512) staged ONCE (128 KB LDS).
// Each wave owns 128 i-rows = 4 isets of 32, processed with 32x32x16 MFMA.
// Only per-iset state lives in registers (~130 VGPR) -> no spill.
// exp2-only softmax (q pre-scaled, scores tiny -> no max subtraction).
__global__ __launch_bounds__(256, 1) void attn_kernel(
    const unsigned short* __restrict__ qT,  // (B,H,L,DK)
    const unsigned short* __restrict__ kT,  // (B,H,L,DK)
    const unsigned short* __restrict__ vv,  // (B,C,L)
    unsigned short* __restrict__ AO) {      // (B,C,L)
  int bh = blockIdx.x, b = bh >> 3, h = bh & 7;
  int tid = threadIdx.x, wave = tid >> 6, lane = tid & 63;
  int l31 = lane & 31, lh = lane >> 5;
  __shared__ __attribute__((aligned(16))) unsigned short Kt[512 * 64];  // [j][d] swz
  __shared__ __attribute__((aligned(16))) unsigned short Vt[64 * 512];  // [d][j] swz
  __shared__ __attribute__((aligned(16))) unsigned short Pt[4][32 * 64];  // per-wave
  __shared__ float lsh[4][32];
  const unsigned short* qh = qT + (size_t)bh * NL * NDK;
  const unsigned short* kh = kT + (size_t)bh * NL * NDK;
  const unsigned short* vh = vv + ((size_t)b * NC + h * NDK) * NL;

  // one-time stage of all K and V (swizzle realized on the global side)
#pragma unroll
  for (int ii = 0; ii < 16; ++ii) {
    int cc = tid + 256 * ii;
    int row = cc >> 3, c = (cc & 7) ^ (row & 7);
    gld16(kh + (size_t)row * NDK + c * 8, &Kt[cc * 8]);
  }
#pragma unroll
  for (int ii = 0; ii < 16; ++ii) {
    int cc = tid + 256 * ii;
    int d = cc >> 6, pc = cc & 63;
    int c = (pc & ~7) | ((pc & 7) ^ (d & 7));
    gld16(vh + (size_t)d * NL + c * 8, &Vt[cc * 8]);
  }
  __syncthreads();  // only barrier in the kernel

  unsigned short* P = &Pt[wave][0];
  for (int iset = 0; iset < 4; ++iset) {
    int i0 = wave * 128 + iset * 32;
    // Q fragments: A[m=i][k=d], m=lane&31, k=(lane>>5)*8 + s*16
    short8 a[4];
#pragma unroll
    for (int s = 0; s < 4; ++s)
      a[s] = *(const short8*)(qh + (size_t)(i0 + l31) * NDK + s * 16 + lh * 8);
    float16v o0, o1;
#pragma unroll
    for (int r = 0; r < 16; ++r) { o0[r] = 0.f; o1[r] = 0.f; }
    float lrun[16];
#pragma unroll
    for (int r = 0; r < 16; ++r) lrun[r] = 0.f;

    for (int jt = 0; jt < 8; ++jt) {
      int j0 = jt * 64;
      // S = Q K^T : 2 n-tiles of 32 j
#pragma unroll
      for (int nt = 0; nt < 2; ++nt) {
        int j = j0 + nt * 32 + l31;
        float16v sacc;
#pragma unroll
        for (int r = 0; r < 16; ++r) sacc[r] = 0.f;
#pragma unroll
        for (int s = 0; s < 4; ++s) {
          int c = (s * 2 + lh) ^ (j & 7);
          short8 kbf = *(const short8*)(&Kt[(size_t)j * 64 + c * 8]);
          sacc = __builtin_amdgcn_mfma_f32_32x32x16_bf16(a[s], kbf, sacc, 0, 0, 0);
        }
        // p = exp2(s); accumulate row sums; write P (row i, col j, swz)
#pragma unroll
        for (int r = 0; r < 16; ++r) {
          float p = __builtin_amdgcn_exp2f(sacc[r]);
          lrun[r] += p;
          int iL = (r & 3) + 8 * (r >> 2) + 4 * lh;
          int col = nt * 32 + l31;
          P[iL * 64 + ((((col >> 3) ^ (iL & 7)) << 3) | (col & 7))] = f2b(p);
        }
      }
      // O += V P^T : A[m=d][k=j] from Vt, B[n=i][k=j] from P
#pragma unroll
      for (int s = 0; s < 4; ++s) {
        int pc = (s * 2 + lh) ^ (l31 & 7);
        short8 pb = *(const short8*)(&P[l31 * 64 + pc * 8]);
        {
          int d = l31;  // dt = 0
          int c = (j0 >> 3) + s * 2 + lh;
          int vc = (c & ~7) | ((c & 7) ^ (d & 7));
          short8 av = *(const short8*)(&Vt[(size_t)d * 512 + vc * 8]);
          o0 = __builtin_amdgcn_mfma_f32_32x32x16_bf16(av, pb, o0, 0, 0, 0);
        }
        {
          int d = 32 + l31;  // dt = 1
          int c = (j0 >> 3) + s * 2 + lh;
          int vc = (c & ~7) | ((c & 7) ^ (d & 7));
          short8 av = *(const short8*)(&Vt[(size_t)d * 512 + vc * 8]);
          o1 = __builtin_amdgcn_mfma_f32_32x32x16_bf16(av, pb, o1, 0, 0, 0);
        }
      }
    }
    // row sums: reduce across the 32 j-lanes of each half
#pragma unroll
    for (int r = 0; r < 16; ++r) {
      float v = lrun[r];
      v += __shfl_xor(v, 1);
      v += __shfl_xor(v, 2);
      v += __shfl_xor(v, 4);
      v += __shfl_xor(v, 8);
      v += __shfl_xor(v, 16);
      lrun[r] = v;
    }
    if (l31 == 0) {
#pragma unroll
      for (int r = 0; r < 16; ++r)
        lsh[wave][(r & 3) + 8 * (r >> 2) + 4 * lh] = lrun[r];
    }
    // same-wave LDS dep: compiler inserts lgkm wait
    float li = __builtin_amdgcn_rcpf(lsh[wave][l31]);
#pragma unroll
    for (int r = 0; r < 16; ++r) {
      int dr = (r & 3) + 8 * (r >> 2) + 4 * lh;
      AO[((size_t)b * NC + h * NDK + dr) * NL + i0 + l31] = f2b(o0[r] * li);
      AO[((size_t)b * NC + h * NDK + 32 + dr) * NL + i0 + l31] = f2b(o1[r] * li);
    }
  }
}

// ---- final projection GEMM (fp32 out) --------------------------------------
__global__ __launch_bounds__(256) void final_gemm_kernel(
    const unsigned short* __restrict__ AO, const unsigned short* __restrict__ W,
    const float* __restrict__ bias, float* __restrict__ out) {
  int b = blockIdx.z;
  __shared__ __attribute__((aligned(16))) unsigned short buf[16384];
  unsigned short* lA = buf;
  unsigned short* lB = buf + 8192;
  int m0 = blockIdx.y * 128, n0 = blockIdx.x * 128;
  float4v acc[4][4];
#pragma unroll
  for (int i = 0; i < 4; ++i)
#pragma unroll
    for (int j = 0; j < 4; ++j) acc[i][j] = (float4v){0.f, 0.f, 0.f, 0.f};
  gemm_core_bk64(AO + (size_t)b * 512 * 512, W, lA, lB, acc, m0, n0);
  int lane = threadIdx.x & 63, quad = lane >> 4, l15 = lane & 15;
  int wave = threadIdx.x >> 6, wr = wave >> 1, wc = wave & 1;
#pragma unroll
  for (int mt = 0; mt < 4; ++mt)
#pragma unroll
    for (int nt = 0; nt < 4; ++nt) {
      int n = n0 + wc * 64 + nt * 16 + l15;
      float bn = bias[n];
#pragma unroll
      for (int r = 0; r < 4; ++r) {
        int m = m0 + wr * 64 + mt * 16 + quad * 4 + r;
        out[((size_t)b * 512 + m) * 512 + n] = acc[mt][nt][r] + bn;
      }
    }
}

extern "C" void kernel_launch(void* const* d_in, const int* in_sizes, int n_in,
                              void* d_out, int out_size, void* d_ws, size_t ws_size,
                              hipStream_t stream) {
  (void)in_sizes; (void)n_in; (void)out_size; (void)ws_size;
  const float* query  = (const float*)d_in[0];
  const float* key    = (const float*)d_in[1];
  const float* value  = (const float*)d_in[2];
  const float* pos    = (const float*)d_in[3];
  const float* proj_w = (const float*)d_in[4];
  const float* proj_b = (const float*)d_in[5];
  const float* q_dw_w = (const float*)d_in[6];
  const float* q_dw_b = (const float*)d_in[7];
  const float* q_pw_w = (const float*)d_in[8];
  const float* q_pw_b = (const float*)d_in[9];
  const float* k_dw_w = (const float*)d_in[10];
  const float* k_dw_b = (const float*)d_in[11];
  const float* k_pw_w = (const float*)d_in[12];
  const float* k_pw_b = (const float*)d_in[13];
  const float* v_dw_w = (const float*)d_in[14];
  const float* v_dw_b = (const float*)d_in[15];
  const float* v_pw_w = (const float*)d_in[16];
  const float* v_pw_b = (const float*)d_in[17];

  char* ws = (char*)d_ws;
  const size_t WMAT = (size_t)512 * 512 * 2;     // 512 KB
  const size_t TEN  = (size_t)NB * NC * NL * 2;  // 16 MB
  unsigned short* wq  = (unsigned short*)(ws);
  unsigned short* wk  = (unsigned short*)(ws + WMAT);
  unsigned short* wv  = (unsigned short*)(ws + 2 * WMAT);
  unsigned short* wp  = (unsigned short*)(ws + 3 * WMAT);
  unsigned short* yq  = (unsigned short*)(ws + 4 * WMAT);
  unsigned short* yk  = (unsigned short*)(ws + 4 * WMAT + TEN);
  unsigned short* yv  = (unsigned short*)(ws + 4 * WMAT + 2 * TEN);
  unsigned short* qT  = (unsigned short*)(ws + 4 * WMAT + 3 * TEN);
  unsigned short* kT  = (unsigned short*)(ws + 4 * WMAT + 4 * TEN);
  unsigned short* vvb = (unsigned short*)(ws + 4 * WMAT + 5 * TEN);
  unsigned short* AO  = yq;  // yq fully consumed by pw(q) before attention writes
  float* pqc = (float*)qT;   // posconv buffers consumed by dw before pw writes qT
  float* pkc = (float*)(ws + 4 * WMAT + 3 * TEN + (size_t)NL * NC * 4);

  cvt4_kernel<<<dim3(256, 4), 256, 0, stream>>>(q_pw_w, k_pw_w, v_pw_w, proj_w, wq, wk, wv, wp);

  posconv_kernel<<<dim3(512, 2), 256, 0, stream>>>(pos, q_dw_w, q_dw_b, k_dw_w, k_dw_b, pqc, pkc);

  dw_kernel<<<dim3(2, 8, 96), 256, 0, stream>>>(
      query, key, value, pqc, pkc, q_dw_w, k_dw_w, v_dw_w, v_dw_b, yq, yk, yv);

  pw_gemm_kernel<<<dim3(4, 4, 96), 256, 0, stream>>>(
      wq, wk, wv, yq, yk, yv, q_pw_b, k_pw_b, v_pw_b, qT, kT, vvb);

  attn_kernel<<<dim3(256), 256, 0, stream>>>(qT, kT, vvb, AO);

  final_gemm_kernel<<<dim3(4, 4, 32), 256, 0, stream>>>(AO, wp, proj_b, (float*)d_out);
}

// Round 6
// 273.606 us; speedup vs baseline: 1.0265x; 1.0265x over previous
//
#include <hip/hip_runtime.h>

typedef __attribute__((ext_vector_type(8))) short short8;
typedef __attribute__((ext_vector_type(4))) float float4v;
typedef __attribute__((ext_vector_type(16))) float float16v;
typedef __attribute__((ext_vector_type(4))) unsigned short ushort4v;

#define NB 32
#define NC 512
#define NL 512
#define NH 8
#define NDK 64

__device__ __forceinline__ unsigned short f2b(float f) {
  union { float f; unsigned int u; } v; v.f = f;
  unsigned int r = v.u + 0x7FFFu + ((v.u >> 16) & 1u);
  return (unsigned short)(r >> 16);
}

__device__ __forceinline__ void gld16(const void* g, void* l) {
  __builtin_amdgcn_global_load_lds(
      (const __attribute__((address_space(1))) unsigned int*)g,
      (__attribute__((address_space(3))) unsigned int*)l, 16, 0, 0);
}

__device__ __forceinline__ float4v bmfma(short8 a, short8 b, float4v c) {
  return __builtin_amdgcn_mfma_f32_16x16x32_bf16(a, b, c, 0, 0, 0);
}

// ---- fused prep: depthwise conv(7) with inline posconv for q,k; plus -------
// ---- fp32->bf16 weight conversion absorbed as extra z-slices ---------------
// dw core is the proven R4 structure: c64 x l64 tile, one barrier, grid of
// 6144 small independent blocks (R5 lesson: intra-block pipelining collapsed
// occupancy 59->31% and regressed; TLP across blocks IS the latency hiding).
// posconv fusion: reference computes conv(x + pos.T), which = conv(x) +
// conv(pos) + bias with the SAME per-channel taps wt[] -- so addv[i] is
// computed inline from 22 coalesced pos reads (L2-hot 1MB map) + 112 FMAs,
// eliminating the separate posconv kernel and its launch.
// cvt4 absorbed at z>=96: 16 z-slices x 64 xy-blocks = 1024 units of 256 thr.
__global__ __launch_bounds__(256) void dw_kernel(
    const float* __restrict__ q, const float* __restrict__ k, const float* __restrict__ v,
    const float* __restrict__ pos,
    const float* __restrict__ qw, const float* __restrict__ kw, const float* __restrict__ vw,
    const float* __restrict__ qb2, const float* __restrict__ kb2, const float* __restrict__ vb,
    const float* __restrict__ cq, const float* __restrict__ ck,
    const float* __restrict__ cv, const float* __restrict__ cp,
    unsigned short* __restrict__ wq, unsigned short* __restrict__ wk,
    unsigned short* __restrict__ wv, unsigned short* __restrict__ wp,
    unsigned short* __restrict__ yq, unsigned short* __restrict__ yk,
    unsigned short* __restrict__ yv) {
  int z = blockIdx.z;
  int tid = threadIdx.x;
  if (z >= 96) {
    // ---- cvt4 job: fp32 -> bf16, 4 matrices of 512x512 ----
    int idx = (z - 96) * 64 + blockIdx.y * 8 + blockIdx.x;
    int m = idx >> 8, blk = idx & 255;
    const float* src = (m == 0) ? cq : (m == 1) ? ck : (m == 2) ? cv : cp;
    unsigned short* dst = (m == 0) ? wq : (m == 1) ? wk : (m == 2) ? wv : wp;
    int i = (blk * 256 + tid) * 4;
    float4v vv = *(const float4v*)(src + i);
    ushort4v o;
    o.x = f2b(vv.x); o.y = f2b(vv.y); o.z = f2b(vv.z); o.w = f2b(vv.w);
    *(ushort4v*)(dst + i) = o;
    return;
  }
  int t = z >> 5, b = z & 31;
  const float* x   = (t == 0) ? q  : (t == 1) ? k  : v;
  const float* dww = (t == 0) ? qw : (t == 1) ? kw : vw;
  const float* dwb = (t == 0) ? qb2 : (t == 1) ? kb2 : vb;
  unsigned short* yT = (t == 0) ? yq : (t == 1) ? yk : yv;
  int c0 = blockIdx.y * 64, l0 = blockIdx.x * 64;
  __shared__ __attribute__((aligned(16))) float xs[64 * 84];
  // stage 64 rows x 20 float4 (l0-8 .. l0+71); 1280 = 5 * 256
#pragma unroll
  for (int it = 0; it < 5; ++it) {
    int idx = tid + 256 * it;
    int row = idx / 20, f4 = idx - row * 20;
    int l = l0 - 8 + f4 * 4;
    float4v vv = {0.f, 0.f, 0.f, 0.f};
    if ((unsigned)l < (unsigned)NL)
      vv = *(const float4v*)(x + ((size_t)b * NC + c0 + row) * NL + l);
    *(float4v*)(xs + row * 84 + f4 * 4) = vv;
  }
  int cl = tid & 63;
  int llb = (tid >> 6) * 16;
  int c = c0 + cl;
  // hoisted independent work: taps, bias, inline posconv (hides under staging)
  float wt[7];
#pragma unroll
  for (int tt = 0; tt < 7; ++tt) wt[tt] = dww[c * 7 + tt];
  float bias0 = dwb[c];
  float addv[16];
  if (t < 2) {
    // addv[i] = dwb[c] + sum_tt pos[l0+llb+i+tt-3, c] * wt[tt]
    float pv[22];
#pragma unroll
    for (int j = 0; j < 22; ++j) {
      int ll = l0 + llb - 3 + j;
      pv[j] = ((unsigned)ll < (unsigned)NL) ? pos[(size_t)ll * NC + c] : 0.f;
    }
#pragma unroll
    for (int i = 0; i < 16; ++i) {
      float acc = bias0;
#pragma unroll
      for (int tt = 0; tt < 7; ++tt) acc += pv[i + tt] * wt[tt];
      addv[i] = acc;
    }
  } else {
#pragma unroll
    for (int i = 0; i < 16; ++i) addv[i] = bias0;
  }
  __syncthreads();
  // per-thread window: w[j] = x[l0 + llb - 4 + j], j = 0..23
  float w[24];
  const float4v* xr = (const float4v*)(xs + cl * 84 + llb + 4);
#pragma unroll
  for (int j = 0; j < 6; ++j) {
    float4v t4 = xr[j];
    w[4 * j] = t4.x; w[4 * j + 1] = t4.y; w[4 * j + 2] = t4.z; w[4 * j + 3] = t4.w;
  }
#pragma unroll
  for (int i = 0; i < 16; ++i) {
    float acc = addv[i];
#pragma unroll
    for (int tt = 0; tt < 7; ++tt) acc += w[i + 1 + tt] * wt[tt];
    yT[((size_t)b * NL + l0 + llb + i) * NC + c] = f2b(acc);
  }
}

// ---- 128x128 MFMA GEMM core, BK=64, global-XOR-swizzled staging ------------
__device__ __forceinline__ void gemm_core_bk64(
    const unsigned short* __restrict__ A, const unsigned short* __restrict__ B,
    unsigned short* lA, unsigned short* lB, float4v acc[4][4], int m0, int n0) {
  int tid = threadIdx.x;
  int lane = tid & 63, quad = lane >> 4, l15 = lane & 15;
  int wave = tid >> 6, wr = wave >> 1, wc = wave & 1;
  const unsigned short* gA[4];
  const unsigned short* gB[4];
  unsigned short* dA[4];
  unsigned short* dB[4];
#pragma unroll
  for (int i = 0; i < 4; ++i) {
    int cc = tid + 256 * i;
    int row = cc >> 3;
    int gc = (cc & 7) ^ (row & 7);
    gA[i] = A + (size_t)(m0 + row) * 512 + gc * 8;
    gB[i] = B + (size_t)(n0 + row) * 512 + gc * 8;
    dA[i] = lA + cc * 8;
    dB[i] = lB + cc * 8;
  }
  for (int k0 = 0; k0 < 512; k0 += 64) {
#pragma unroll
    for (int i = 0; i < 4; ++i) gld16(gA[i] + k0, dA[i]);
#pragma unroll
    for (int i = 0; i < 4; ++i) gld16(gB[i] + k0, dB[i]);
    __syncthreads();
#pragma unroll
    for (int ks = 0; ks < 2; ++ks) {
      int sw = (ks * 4 + quad) ^ (l15 & 7);
      short8 af[4], bf[4];
#pragma unroll
      for (int mt = 0; mt < 4; ++mt)
        af[mt] = *(const short8*)(lA + (wr * 64 + mt * 16 + l15) * 64 + sw * 8);
#pragma unroll
      for (int nt = 0; nt < 4; ++nt)
        bf[nt] = *(const short8*)(lB + (wc * 64 + nt * 16 + l15) * 64 + sw * 8);
#pragma unroll
      for (int mt = 0; mt < 4; ++mt)
#pragma unroll
        for (int nt = 0; nt < 4; ++nt)
          acc[mt][nt] = bmfma(af[mt], bf[nt], acc[mt][nt]);
    }
    __syncthreads();
  }
}

// ---- fused pointwise GEMMs for q,k,v ---------------------------------------
// q output is pre-scaled by 0.125*log2(e) so attention can use exp2 directly.
// Epilogue uses scalar LDS writes (short live ranges -> ~108 VGPR, 4 blocks/CU)
// with XOR-swizzled m-index (bits 3-5 ^= nloc&7) to kill the 16-way conflict.
__global__ __launch_bounds__(256) void pw_gemm_kernel(
    const unsigned short* __restrict__ wqm, const unsigned short* __restrict__ wkm,
    const unsigned short* __restrict__ wvm,
    const unsigned short* __restrict__ yq, const unsigned short* __restrict__ yk,
    const unsigned short* __restrict__ yv,
    const float* __restrict__ qb, const float* __restrict__ kb, const float* __restrict__ vb,
    unsigned short* __restrict__ qT, unsigned short* __restrict__ kT,
    unsigned short* __restrict__ vvo) {
  int z = blockIdx.z, t = z >> 5, b = z & 31;
  const unsigned short* W = (t == 0) ? wqm : (t == 1) ? wkm : wvm;
  const unsigned short* Y = ((t == 0) ? yq : (t == 1) ? yk : yv) + (size_t)b * NL * NC;
  const float* bias = (t == 0) ? qb : (t == 1) ? kb : vb;
  unsigned short* out = (t == 0) ? qT : (t == 1) ? kT : vvo;
  float oscale = (t == 0) ? 0.18033688011112042f : 1.0f;  // 0.125*log2(e) folded into q
  __shared__ __attribute__((aligned(16))) unsigned short buf[16384];
  unsigned short* lA = buf;
  unsigned short* lB = buf + 8192;
  int m0 = blockIdx.y * 128, n0 = blockIdx.x * 128;
  float4v acc[4][4];
#pragma unroll
  for (int i = 0; i < 4; ++i)
#pragma unroll
    for (int j = 0; j < 4; ++j) acc[i][j] = (float4v){0.f, 0.f, 0.f, 0.f};
  gemm_core_bk64(W, Y, lA, lB, acc, m0, n0);
  int tid = threadIdx.x;
  int lane = tid & 63, quad = lane >> 4, l15 = lane & 15;
  int wave = tid >> 6, wr = wave >> 1, wc = wave & 1;
  if (t < 2) {
    // transpose epilogue through LDS: scalar writes, XOR-swizzled m-index;
    // read side inverts with dc ^ (l&7).
#pragma unroll
    for (int mt = 0; mt < 4; ++mt) {
      int mloc = wr * 64 + mt * 16 + quad * 4;
#pragma unroll
      for (int nt = 0; nt < 4; ++nt) {
        int nloc = wc * 64 + nt * 16 + l15;
        int sx = (nloc & 7) << 3;
#pragma unroll
        for (int r = 0; r < 4; ++r) {
          int ml = mloc + r;
          buf[(ml >> 6) * 8192 + nloc * 64 + ((ml & 63) ^ sx)] =
              f2b((acc[mt][nt][r] + bias[m0 + ml]) * oscale);
        }
      }
    }
    __syncthreads();
#pragma unroll
    for (int it = 0; it < 8; ++it) {
      int cc = tid + it * 256;
      int hloc = cc >> 10, l = (cc >> 3) & 127, dc = cc & 7;
      short8 vd = *(const short8*)(buf + hloc * 8192 + l * 64 + ((dc ^ (l & 7)) << 3));
      *(short8*)(out + (((size_t)b * NH + (m0 >> 6) + hloc) * NL + n0 + l) * NDK + dc * 8) = vd;
    }
  } else {
#pragma unroll
    for (int mt = 0; mt < 4; ++mt)
#pragma unroll
      for (int nt = 0; nt < 4; ++nt) {
        int n = n0 + wc * 64 + nt * 16 + l15;
#pragma unroll
        for (int r = 0; r < 4; ++r) {
          int m = m0 + wr * 64 + mt * 16 + quad * 4 + r;
          out[((size_t)b * NC + m) * NL + n] = f2b(acc[mt][nt][r] + bias[m]);
        }
      }
  }
}

// ---- persistent attention, i-outer / j-inner: full K,V resident in LDS -----
// One block per (b,h). K (512x64) + V (64x512) staged ONCE (128 KB LDS).
// Each wave owns 128 i-rows = 4 isets of 32, processed with 32x32x16 MFMA.
// Only per-iset state lives in registers (~130 VGPR) -> no spill.
// exp2-only softmax (q pre-scaled, scores tiny -> no max subtraction).
__global__ __launch_bounds__(256, 1) void attn_kernel(
    const unsigned short* __restrict__ qT,  // (B,H,L,DK)
    const unsigned short* __restrict__ kT,  // (B,H,L,DK)
    const unsigned short* __restrict__ vv,  // (B,C,L)
    unsigned short* __restrict__ AO) {      // (B,C,L)
  int bh = blockIdx.x, b = bh >> 3, h = bh & 7;
  int tid = threadIdx.x, wave = tid >> 6, lane = tid & 63;
  int l31 = lane & 31, lh = lane >> 5;
  __shared__ __attribute__((aligned(16))) unsigned short Kt[512 * 64];  // [j][d] swz
  __shared__ __attribute__((aligned(16))) unsigned short Vt[64 * 512];  // [d][j] swz
  __shared__ __attribute__((aligned(16))) unsigned short Pt[4][32 * 64];  // per-wave
  __shared__ float lsh[4][32];
  const unsigned short* qh = qT + (size_t)bh * NL * NDK;
  const unsigned short* kh = kT + (size_t)bh * NL * NDK;
  const unsigned short* vh = vv + ((size_t)b * NC + h * NDK) * NL;

  // one-time stage of all K and V (swizzle realized on the global side)
#pragma unroll
  for (int ii = 0; ii < 16; ++ii) {
    int cc = tid + 256 * ii;
    int row = cc >> 3, c = (cc & 7) ^ (row & 7);
    gld16(kh + (size_t)row * NDK + c * 8, &Kt[cc * 8]);
  }
#pragma unroll
  for (int ii = 0; ii < 16; ++ii) {
    int cc = tid + 256 * ii;
    int d = cc >> 6, pc = cc & 63;
    int c = (pc & ~7) | ((pc & 7) ^ (d & 7));
    gld16(vh + (size_t)d * NL + c * 8, &Vt[cc * 8]);
  }
  __syncthreads();  // only barrier in the kernel

  unsigned short* P = &Pt[wave][0];
  for (int iset = 0; iset < 4; ++iset) {
    int i0 = wave * 128 + iset * 32;
    // Q fragments: A[m=i][k=d], m=lane&31, k=(lane>>5)*8 + s*16
    short8 a[4];
#pragma unroll
    for (int s = 0; s < 4; ++s)
      a[s] = *(const short8*)(qh + (size_t)(i0 + l31) * NDK + s * 16 + lh * 8);
    float16v o0, o1;
#pragma unroll
    for (int r = 0; r < 16; ++r) { o0[r] = 0.f; o1[r] = 0.f; }
    float lrun[16];
#pragma unroll
    for (int r = 0; r < 16; ++r) lrun[r] = 0.f;

    for (int jt = 0; jt < 8; ++jt) {
      int j0 = jt * 64;
      // S = Q K^T : 2 n-tiles of 32 j
#pragma unroll
      for (int nt = 0; nt < 2; ++nt) {
        int j = j0 + nt * 32 + l31;
        float16v sacc;
#pragma unroll
        for (int r = 0; r < 16; ++r) sacc[r] = 0.f;
#pragma unroll
        for (int s = 0; s < 4; ++s) {
          int c = (s * 2 + lh) ^ (j & 7);
          short8 kbf = *(const short8*)(&Kt[(size_t)j * 64 + c * 8]);
          sacc = __builtin_amdgcn_mfma_f32_32x32x16_bf16(a[s], kbf, sacc, 0, 0, 0);
        }
        // p = exp2(s); accumulate row sums; write P (row i, col j, swz)
#pragma unroll
        for (int r = 0; r < 16; ++r) {
          float p = __builtin_amdgcn_exp2f(sacc[r]);
          lrun[r] += p;
          int iL = (r & 3) + 8 * (r >> 2) + 4 * lh;
          int col = nt * 32 + l31;
          P[iL * 64 + ((((col >> 3) ^ (iL & 7)) << 3) | (col & 7))] = f2b(p);
        }
      }
      // O += V P^T : A[m=d][k=j] from Vt, B[n=i][k=j] from P
#pragma unroll
      for (int s = 0; s < 4; ++s) {
        int pc = (s * 2 + lh) ^ (l31 & 7);
        short8 pb = *(const short8*)(&P[l31 * 64 + pc * 8]);
        {
          int d = l31;  // dt = 0
          int c = (j0 >> 3) + s * 2 + lh;
          int vc = (c & ~7) | ((c & 7) ^ (d & 7));
          short8 av = *(const short8*)(&Vt[(size_t)d * 512 + vc * 8]);
          o0 = __builtin_amdgcn_mfma_f32_32x32x16_bf16(av, pb, o0, 0, 0, 0);
        }
        {
          int d = 32 + l31;  // dt = 1
          int c = (j0 >> 3) + s * 2 + lh;
          int vc = (c & ~7) | ((c & 7) ^ (d & 7));
          short8 av = *(const short8*)(&Vt[(size_t)d * 512 + vc * 8]);
          o1 = __builtin_amdgcn_mfma_f32_32x32x16_bf16(av, pb, o1, 0, 0, 0);
        }
      }
    }
    // row sums: reduce across the 32 j-lanes of each half
#pragma unroll
    for (int r = 0; r < 16; ++r) {
      float v = lrun[r];
      v += __shfl_xor(v, 1);
      v += __shfl_xor(v, 2);
      v += __shfl_xor(v, 4);
      v += __shfl_xor(v, 8);
      v += __shfl_xor(v, 16);
      lrun[r] = v;
    }
    if (l31 == 0) {
#pragma unroll
      for (int r = 0; r < 16; ++r)
        lsh[wave][(r & 3) + 8 * (r >> 2) + 4 * lh] = lrun[r];
    }
    // same-wave LDS dep: compiler inserts lgkm wait
    float li = __builtin_amdgcn_rcpf(lsh[wave][l31]);
#pragma unroll
    for (int r = 0; r < 16; ++r) {
      int dr = (r & 3) + 8 * (r >> 2) + 4 * lh;
      AO[((size_t)b * NC + h * NDK + dr) * NL + i0 + l31] = f2b(o0[r] * li);
      AO[((size_t)b * NC + h * NDK + 32 + dr) * NL + i0 + l31] = f2b(o1[r] * li);
    }
  }
}

// ---- final projection GEMM (fp32 out) --------------------------------------
__global__ __launch_bounds__(256) void final_gemm_kernel(
    const unsigned short* __restrict__ AO, const unsigned short* __restrict__ W,
    const float* __restrict__ bias, float* __restrict__ out) {
  int b = blockIdx.z;
  __shared__ __attribute__((aligned(16))) unsigned short buf[16384];
  unsigned short* lA = buf;
  unsigned short* lB = buf + 8192;
  int m0 = blockIdx.y * 128, n0 = blockIdx.x * 128;
  float4v acc[4][4];
#pragma unroll
  for (int i = 0; i < 4; ++i)
#pragma unroll
    for (int j = 0; j < 4; ++j) acc[i][j] = (float4v){0.f, 0.f, 0.f, 0.f};
  gemm_core_bk64(AO + (size_t)b * 512 * 512, W, lA, lB, acc, m0, n0);
  int lane = threadIdx.x & 63, quad = lane >> 4, l15 = lane & 15;
  int wave = threadIdx.x >> 6, wr = wave >> 1, wc = wave & 1;
#pragma unroll
  for (int mt = 0; mt < 4; ++mt)
#pragma unroll
    for (int nt = 0; nt < 4; ++nt) {
      int n = n0 + wc * 64 + nt * 16 + l15;
      float bn = bias[n];
#pragma unroll
      for (int r = 0; r < 4; ++r) {
        int m = m0 + wr * 64 + mt * 16 + quad * 4 + r;
        out[((size_t)b * 512 + m) * 512 + n] = acc[mt][nt][r] + bn;
      }
    }
}

extern "C" void kernel_launch(void* const* d_in, const int* in_sizes, int n_in,
                              void* d_out, int out_size, void* d_ws, size_t ws_size,
                              hipStream_t stream) {
  (void)in_sizes; (void)n_in; (void)out_size; (void)ws_size;
  const float* query  = (const float*)d_in[0];
  const float* key    = (const float*)d_in[1];
  const float* value  = (const float*)d_in[2];
  const float* pos    = (const float*)d_in[3];
  const float* proj_w = (const float*)d_in[4];
  const float* proj_b = (const float*)d_in[5];
  const float* q_dw_w = (const float*)d_in[6];
  const float* q_dw_b = (const float*)d_in[7];
  const float* q_pw_w = (const float*)d_in[8];
  const float* q_pw_b = (const float*)d_in[9];
  const float* k_dw_w = (const float*)d_in[10];
  const float* k_dw_b = (const float*)d_in[11];
  const float* k_pw_w = (const float*)d_in[12];
  const float* k_pw_b = (const float*)d_in[13];
  const float* v_dw_w = (const float*)d_in[14];
  const float* v_dw_b = (const float*)d_in[15];
  const float* v_pw_w = (const float*)d_in[16];
  const float* v_pw_b = (const float*)d_in[17];

  char* ws = (char*)d_ws;
  const size_t WMAT = (size_t)512 * 512 * 2;     // 512 KB
  const size_t TEN  = (size_t)NB * NC * NL * 2;  // 16 MB
  unsigned short* wq  = (unsigned short*)(ws);
  unsigned short* wk  = (unsigned short*)(ws + WMAT);
  unsigned short* wv  = (unsigned short*)(ws + 2 * WMAT);
  unsigned short* wp  = (unsigned short*)(ws + 3 * WMAT);
  unsigned short* yq  = (unsigned short*)(ws + 4 * WMAT);
  unsigned short* yk  = (unsigned short*)(ws + 4 * WMAT + TEN);
  unsigned short* yv  = (unsigned short*)(ws + 4 * WMAT + 2 * TEN);
  unsigned short* qT  = (unsigned short*)(ws + 4 * WMAT + 3 * TEN);
  unsigned short* kT  = (unsigned short*)(ws + 4 * WMAT + 4 * TEN);
  unsigned short* vvb = (unsigned short*)(ws + 4 * WMAT + 5 * TEN);
  unsigned short* AO  = yq;  // yq fully consumed by pw(q) before attention writes

  // fused prep: dw-conv (z<96, with inline posconv for q,k) + cvt4 (z>=96)
  dw_kernel<<<dim3(8, 8, 112), 256, 0, stream>>>(
      query, key, value, pos,
      q_dw_w, k_dw_w, v_dw_w, q_dw_b, k_dw_b, v_dw_b,
      q_pw_w, k_pw_w, v_pw_w, proj_w, wq, wk, wv, wp,
      yq, yk, yv);

  pw_gemm_kernel<<<dim3(4, 4, 96), 256, 0, stream>>>(
      wq, wk, wv, yq, yk, yv, q_pw_b, k_pw_b, v_pw_b, qT, kT, vvb);

  attn_kernel<<<dim3(256), 256, 0, stream>>>(qT, kT, vvb, AO);

  final_gemm_kernel<<<dim3(4, 4, 32), 256, 0, stream>>>(AO, wp, proj_b, (float*)d_out);
}

// Round 8
// 269.410 us; speedup vs baseline: 1.0425x; 1.0156x over previous
//
#include <hip/hip_runtime.h>

typedef __attribute__((ext_vector_type(8))) short short8;
typedef __attribute__((ext_vector_type(4))) float float4v;
typedef __attribute__((ext_vector_type(16))) float float16v;
typedef __attribute__((ext_vector_type(4))) unsigned short ushort4v;

#define NB 32
#define NC 512
#define NL 512
#define NH 8
#define NDK 64

__device__ __forceinline__ unsigned short f2b(float f) {
  union { float f; unsigned int u; } v; v.f = f;
  unsigned int r = v.u + 0x7FFFu + ((v.u >> 16) & 1u);
  return (unsigned short)(r >> 16);
}

__device__ __forceinline__ void gld16(const void* g, void* l) {
  __builtin_amdgcn_global_load_lds(
      (const __attribute__((address_space(1))) unsigned int*)g,
      (__attribute__((address_space(3))) unsigned int*)l, 16, 0, 0);
}

__device__ __forceinline__ float4v bmfma(short8 a, short8 b, float4v c) {
  return __builtin_amdgcn_mfma_f32_16x16x32_bf16(a, b, c, 0, 0, 0);
}

// ---- fused prep: depthwise conv(7) with inline posconv for q,k; plus -------
// ---- fp32->bf16 weight conversion absorbed as extra z-slices ---------------
// dw core: c64 x l64 tile, one barrier, 6144 independent blocks.
// R7 NaN root cause: gld16 inside a per-lane branch. global_load_lds's LDS
// dest is WAVE-UNIFORM base + lane*16 (m104) -- predicating it shifts every
// active lane's destination. R8 fix: every wave fully active -- all 1344
// cells (incl. pad f4==20 and OOB halo) issue gld16 with a CLAMPED global
// address. Garbage in pad cells is never read (compute reads fi 4..75, pad
// is 80..83); garbage in OOB halo cells is read only by one wave-uniform
// (block, llb) pair per edge, zeroed in registers after the window load.
// Stride 84 == 20 mod 32 keeps the 64-lane b128 compute reads conflict-free.
__global__ __launch_bounds__(256) void dw_kernel(
    const float* __restrict__ q, const float* __restrict__ k, const float* __restrict__ v,
    const float* __restrict__ pos,
    const float* __restrict__ qw, const float* __restrict__ kw, const float* __restrict__ vw,
    const float* __restrict__ qb2, const float* __restrict__ kb2, const float* __restrict__ vb,
    const float* __restrict__ cq, const float* __restrict__ ck,
    const float* __restrict__ cv, const float* __restrict__ cp,
    unsigned short* __restrict__ wq, unsigned short* __restrict__ wk,
    unsigned short* __restrict__ wv, unsigned short* __restrict__ wp,
    unsigned short* __restrict__ yq, unsigned short* __restrict__ yk,
    unsigned short* __restrict__ yv) {
  int z = blockIdx.z;
  int tid = threadIdx.x;
  if (z >= 96) {
    // ---- cvt4 job: fp32 -> bf16, 4 matrices of 512x512 ----
    int idx = (z - 96) * 64 + blockIdx.y * 8 + blockIdx.x;
    int m = idx >> 8, blk = idx & 255;
    const float* src = (m == 0) ? cq : (m == 1) ? ck : (m == 2) ? cv : cp;
    unsigned short* dst = (m == 0) ? wq : (m == 1) ? wk : (m == 2) ? wv : wp;
    int i = (blk * 256 + tid) * 4;
    float4v vv = *(const float4v*)(src + i);
    ushort4v o;
    o.x = f2b(vv.x); o.y = f2b(vv.y); o.z = f2b(vv.z); o.w = f2b(vv.w);
    *(ushort4v*)(dst + i) = o;
    return;
  }
  int t = z >> 5, b = z & 31;
  const float* x   = (t == 0) ? q  : (t == 1) ? k  : v;
  const float* dww = (t == 0) ? qw : (t == 1) ? kw : vw;
  const float* dwb = (t == 0) ? qb2 : (t == 1) ? kb2 : vb;
  unsigned short* yT = (t == 0) ? yq : (t == 1) ? yk : yv;
  int c0 = blockIdx.y * 64, l0 = blockIdx.x * 64;
  __shared__ __attribute__((aligned(16))) float xs[64 * 84];
  // stage 64 rows x 21 cells; 1344 = 5.25*256 (it=5: wave 0 fully active,
  // waves 1-3 fully inactive -> wave-uniform). ALL lanes of an active wave
  // issue gld16 (clamped address) -> linear lane mapping preserved.
#pragma unroll
  for (int it = 0; it < 6; ++it) {
    int idx = tid + 256 * it;
    if (idx < 1344) {
      int row = idx / 21, f4 = idx - row * 21;
      int l = l0 - 8 + f4 * 4;
      int lc = l < 0 ? 0 : (l > NL - 4 ? NL - 4 : l);
      gld16(x + ((size_t)b * NC + c0 + row) * NL + lc, xs + idx * 4);
    }
  }
  int cl = tid & 63;
  int llb = (tid >> 6) * 16;
  int c = c0 + cl;
  // hoisted independent work: taps, bias, inline posconv (hides under staging)
  float wt[7];
#pragma unroll
  for (int tt = 0; tt < 7; ++tt) wt[tt] = dww[c * 7 + tt];
  float bias0 = dwb[c];
  float addv[16];
  if (t < 2) {
    // addv[i] = dwb[c] + sum_tt pos[l0+llb+i+tt-3, c] * wt[tt]
    float pv[22];
#pragma unroll
    for (int j = 0; j < 22; ++j) {
      int ll = l0 + llb - 3 + j;
      pv[j] = ((unsigned)ll < (unsigned)NL) ? pos[(size_t)ll * NC + c] : 0.f;
    }
#pragma unroll
    for (int i = 0; i < 16; ++i) {
      float acc = bias0;
#pragma unroll
      for (int tt = 0; tt < 7; ++tt) acc += pv[i + tt] * wt[tt];
      addv[i] = acc;
    }
  } else {
#pragma unroll
    for (int i = 0; i < 16; ++i) addv[i] = bias0;
  }
  __syncthreads();
  // per-thread window: w[j] = x[l0 + llb - 4 + j], j = 0..23
  float w[24];
  const float4v* xr = (const float4v*)(xs + cl * 84 + llb + 4);
#pragma unroll
  for (int j = 0; j < 6; ++j) {
    float4v t4 = xr[j];
    w[4 * j] = t4.x; w[4 * j + 1] = t4.y; w[4 * j + 2] = t4.z; w[4 * j + 3] = t4.w;
  }
  // zero the OOB taps (clamped-load garbage). llb is wave-uniform -> both
  // branches are wave-uniform; only edge blocks take them.
  if (blockIdx.x == 0 && llb == 0) {
    w[0] = 0.f; w[1] = 0.f; w[2] = 0.f; w[3] = 0.f;
  } else if (blockIdx.x == 7 && llb == 48) {
    w[20] = 0.f; w[21] = 0.f; w[22] = 0.f; w[23] = 0.f;
  }
#pragma unroll
  for (int i = 0; i < 16; ++i) {
    float acc = addv[i];
#pragma unroll
    for (int tt = 0; tt < 7; ++tt) acc += w[i + 1 + tt] * wt[tt];
    yT[((size_t)b * NL + l0 + llb + i) * NC + c] = f2b(acc);
  }
}

// ---- 128x128 MFMA GEMM core, BK=64, global-XOR-swizzled staging ------------
__device__ __forceinline__ void gemm_core_bk64(
    const unsigned short* __restrict__ A, const unsigned short* __restrict__ B,
    unsigned short* lA, unsigned short* lB, float4v acc[4][4], int m0, int n0) {
  int tid = threadIdx.x;
  int lane = tid & 63, quad = lane >> 4, l15 = lane & 15;
  int wave = tid >> 6, wr = wave >> 1, wc = wave & 1;
  const unsigned short* gA[4];
  const unsigned short* gB[4];
  unsigned short* dA[4];
  unsigned short* dB[4];
#pragma unroll
  for (int i = 0; i < 4; ++i) {
    int cc = tid + 256 * i;
    int row = cc >> 3;
    int gc = (cc & 7) ^ (row & 7);
    gA[i] = A + (size_t)(m0 + row) * 512 + gc * 8;
    gB[i] = B + (size_t)(n0 + row) * 512 + gc * 8;
    dA[i] = lA + cc * 8;
    dB[i] = lB + cc * 8;
  }
  for (int k0 = 0; k0 < 512; k0 += 64) {
#pragma unroll
    for (int i = 0; i < 4; ++i) gld16(gA[i] + k0, dA[i]);
#pragma unroll
    for (int i = 0; i < 4; ++i) gld16(gB[i] + k0, dB[i]);
    __syncthreads();
#pragma unroll
    for (int ks = 0; ks < 2; ++ks) {
      int sw = (ks * 4 + quad) ^ (l15 & 7);
      short8 af[4], bf[4];
#pragma unroll
      for (int mt = 0; mt < 4; ++mt)
        af[mt] = *(const short8*)(lA + (wr * 64 + mt * 16 + l15) * 64 + sw * 8);
#pragma unroll
      for (int nt = 0; nt < 4; ++nt)
        bf[nt] = *(const short8*)(lB + (wc * 64 + nt * 16 + l15) * 64 + sw * 8);
#pragma unroll
      for (int mt = 0; mt < 4; ++mt)
#pragma unroll
        for (int nt = 0; nt < 4; ++nt)
          acc[mt][nt] = bmfma(af[mt], bf[nt], acc[mt][nt]);
    }
    __syncthreads();
  }
}

// ---- fused pointwise GEMMs for q,k,v ---------------------------------------
// q output is pre-scaled by 0.125*log2(e) so attention can use exp2 directly.
// q/k epilogue: LDS transpose in [n][m] layout, XOR-swizzled m-index.
// v epilogue: LDS transpose in [m][n] layout, XOR-swizzled n-index ->
// short8 n-contiguous stores (old path: 64 scalar u16 stores/thread touching
// 4 cache lines each at 1KB stride).
__global__ __launch_bounds__(256) void pw_gemm_kernel(
    const unsigned short* __restrict__ wqm, const unsigned short* __restrict__ wkm,
    const unsigned short* __restrict__ wvm,
    const unsigned short* __restrict__ yq, const unsigned short* __restrict__ yk,
    const unsigned short* __restrict__ yv,
    const float* __restrict__ qb, const float* __restrict__ kb, const float* __restrict__ vb,
    unsigned short* __restrict__ qT, unsigned short* __restrict__ kT,
    unsigned short* __restrict__ vvo) {
  int z = blockIdx.z, t = z >> 5, b = z & 31;
  const unsigned short* W = (t == 0) ? wqm : (t == 1) ? wkm : wvm;
  const unsigned short* Y = ((t == 0) ? yq : (t == 1) ? yk : yv) + (size_t)b * NL * NC;
  const float* bias = (t == 0) ? qb : (t == 1) ? kb : vb;
  unsigned short* out = (t == 0) ? qT : (t == 1) ? kT : vvo;
  float oscale = (t == 0) ? 0.18033688011112042f : 1.0f;  // 0.125*log2(e) folded into q
  __shared__ __attribute__((aligned(16))) unsigned short buf[16384];
  unsigned short* lA = buf;
  unsigned short* lB = buf + 8192;
  int m0 = blockIdx.y * 128, n0 = blockIdx.x * 128;
  float4v acc[4][4];
#pragma unroll
  for (int i = 0; i < 4; ++i)
#pragma unroll
    for (int j = 0; j < 4; ++j) acc[i][j] = (float4v){0.f, 0.f, 0.f, 0.f};
  gemm_core_bk64(W, Y, lA, lB, acc, m0, n0);
  int tid = threadIdx.x;
  int lane = tid & 63, quad = lane >> 4, l15 = lane & 15;
  int wave = tid >> 6, wr = wave >> 1, wc = wave & 1;
  if (t < 2) {
    // transpose epilogue through LDS: scalar writes, XOR-swizzled m-index;
    // read side inverts with dc ^ (l&7).
#pragma unroll
    for (int mt = 0; mt < 4; ++mt) {
      int mloc = wr * 64 + mt * 16 + quad * 4;
#pragma unroll
      for (int nt = 0; nt < 4; ++nt) {
        int nloc = wc * 64 + nt * 16 + l15;
        int sx = (nloc & 7) << 3;
#pragma unroll
        for (int r = 0; r < 4; ++r) {
          int ml = mloc + r;
          buf[(ml >> 6) * 8192 + nloc * 64 + ((ml & 63) ^ sx)] =
              f2b((acc[mt][nt][r] + bias[m0 + ml]) * oscale);
        }
      }
    }
    __syncthreads();
#pragma unroll
    for (int it = 0; it < 8; ++it) {
      int cc = tid + it * 256;
      int hloc = cc >> 10, l = (cc >> 3) & 127, dc = cc & 7;
      short8 vd = *(const short8*)(buf + hloc * 8192 + l * 64 + ((dc ^ (l & 7)) << 3));
      *(short8*)(out + (((size_t)b * NH + (m0 >> 6) + hloc) * NL + n0 + l) * NDK + dc * 8) = vd;
    }
  } else {
    // v transpose epilogue through LDS ([m][n], swizzle on n bits 3-5):
    // read inverts with dc ^ (m&7); stores are short8 n-contiguous.
#pragma unroll
    for (int mt = 0; mt < 4; ++mt) {
      int mloc = wr * 64 + mt * 16 + quad * 4;
#pragma unroll
      for (int nt = 0; nt < 4; ++nt) {
        int nloc = wc * 64 + nt * 16 + l15;
#pragma unroll
        for (int r = 0; r < 4; ++r) {
          int ml = mloc + r;
          buf[(ml >> 6) * 8192 + (ml & 63) * 128 + (nloc ^ ((ml & 7) << 3))] =
              f2b(acc[mt][nt][r] + bias[m0 + ml]);
        }
      }
    }
    __syncthreads();
#pragma unroll
    for (int it = 0; it < 8; ++it) {
      int cc = tid + it * 256;
      int half = cc >> 10, m = (cc >> 4) & 63, dc = cc & 15;
      short8 vd = *(const short8*)(buf + half * 8192 + m * 128 + ((dc ^ (m & 7)) << 3));
      *(short8*)(out + ((size_t)b * NC + m0 + half * 64 + m) * NL + n0 + dc * 8) = vd;
    }
  }
}

// ---- persistent attention, i-outer / j-inner: full K,V resident in LDS -----
// One block per (b,h). K (512x64) + V (64x512) staged ONCE (128 KB LDS).
// Each wave owns 128 i-rows = 4 isets of 32, processed with 32x32x16 MFMA.
// Only per-iset state lives in registers (~130 VGPR) -> no spill.
// exp2-only softmax (q pre-scaled, scores tiny -> no max subtraction).
__global__ __launch_bounds__(256, 1) void attn_kernel(
    const unsigned short* __restrict__ qT,  // (B,H,L,DK)
    const unsigned short* __restrict__ kT,  // (B,H,L,DK)
    const unsigned short* __restrict__ vv,  // (B,C,L)
    unsigned short* __restrict__ AO) {      // (B,C,L)
  int bh = blockIdx.x, b = bh >> 3, h = bh & 7;
  int tid = threadIdx.x, wave = tid >> 6, lane = tid & 63;
  int l31 = lane & 31, lh = lane >> 5;
  __shared__ __attribute__((aligned(16))) unsigned short Kt[512 * 64];  // [j][d] swz
  __shared__ __attribute__((aligned(16))) unsigned short Vt[64 * 512];  // [d][j] swz
  __shared__ __attribute__((aligned(16))) unsigned short Pt[4][32 * 64];  // per-wave
  __shared__ float lsh[4][32];
  const unsigned short* qh = qT + (size_t)bh * NL * NDK;
  const unsigned short* kh = kT + (size_t)bh * NL * NDK;
  const unsigned short* vh = vv + ((size_t)b * NC + h * NDK) * NL;

  // one-time stage of all K and V (swizzle realized on the global side)
#pragma unroll
  for (int ii = 0; ii < 16; ++ii) {
    int cc = tid + 256 * ii;
    int row = cc >> 3, c = (cc & 7) ^ (row & 7);
    gld16(kh + (size_t)row * NDK + c * 8, &Kt[cc * 8]);
  }
#pragma unroll
  for (int ii = 0; ii < 16; ++ii) {
    int cc = tid + 256 * ii;
    int d = cc >> 6, pc = cc & 63;
    int c = (pc & ~7) | ((pc & 7) ^ (d & 7));
    gld16(vh + (size_t)d * NL + c * 8, &Vt[cc * 8]);
  }
  __syncthreads();  // only barrier in the kernel

  unsigned short* P = &Pt[wave][0];
  for (int iset = 0; iset < 4; ++iset) {
    int i0 = wave * 128 + iset * 32;
    // Q fragments: A[m=i][k=d], m=lane&31, k=(lane>>5)*8 + s*16
    short8 a[4];
#pragma unroll
    for (int s = 0; s < 4; ++s)
      a[s] = *(const short8*)(qh + (size_t)(i0 + l31) * NDK + s * 16 + lh * 8);
    float16v o0, o1;
#pragma unroll
    for (int r = 0; r < 16; ++r) { o0[r] = 0.f; o1[r] = 0.f; }
    float lrun[16];
#pragma unroll
    for (int r = 0; r < 16; ++r) lrun[r] = 0.f;

    for (int jt = 0; jt < 8; ++jt) {
      int j0 = jt * 64;
      // S = Q K^T : 2 n-tiles of 32 j
#pragma unroll
      for (int nt = 0; nt < 2; ++nt) {
        int j = j0 + nt * 32 + l31;
        float16v sacc;
#pragma unroll
        for (int r = 0; r < 16; ++r) sacc[r] = 0.f;
#pragma unroll
        for (int s = 0; s < 4; ++s) {
          int c = (s * 2 + lh) ^ (j & 7);
          short8 kbf = *(const short8*)(&Kt[(size_t)j * 64 + c * 8]);
          sacc = __builtin_amdgcn_mfma_f32_32x32x16_bf16(a[s], kbf, sacc, 0, 0, 0);
        }
        // p = exp2(s); accumulate row sums; write P (row i, col j, swz)
#pragma unroll
        for (int r = 0; r < 16; ++r) {
          float p = __builtin_amdgcn_exp2f(sacc[r]);
          lrun[r] += p;
          int iL = (r & 3) + 8 * (r >> 2) + 4 * lh;
          int col = nt * 32 + l31;
          P[iL * 64 + ((((col >> 3) ^ (iL & 7)) << 3) | (col & 7))] = f2b(p);
        }
      }
      // O += V P^T : A[m=d][k=j] from Vt, B[n=i][k=j] from P
#pragma unroll
      for (int s = 0; s < 4; ++s) {
        int pc = (s * 2 + lh) ^ (l31 & 7);
        short8 pb = *(const short8*)(&P[l31 * 64 + pc * 8]);
        {
          int d = l31;  // dt = 0
          int c = (j0 >> 3) + s * 2 + lh;
          int vc = (c & ~7) | ((c & 7) ^ (d & 7));
          short8 av = *(const short8*)(&Vt[(size_t)d * 512 + vc * 8]);
          o0 = __builtin_amdgcn_mfma_f32_32x32x16_bf16(av, pb, o0, 0, 0, 0);
        }
        {
          int d = 32 + l31;  // dt = 1
          int c = (j0 >> 3) + s * 2 + lh;
          int vc = (c & ~7) | ((c & 7) ^ (d & 7));
          short8 av = *(const short8*)(&Vt[(size_t)d * 512 + vc * 8]);
          o1 = __builtin_amdgcn_mfma_f32_32x32x16_bf16(av, pb, o1, 0, 0, 0);
        }
      }
    }
    // row sums: reduce across the 32 j-lanes of each half
#pragma unroll
    for (int r = 0; r < 16; ++r) {
      float v = lrun[r];
      v += __shfl_xor(v, 1);
      v += __shfl_xor(v, 2);
      v += __shfl_xor(v, 4);
      v += __shfl_xor(v, 8);
      v += __shfl_xor(v, 16);
      lrun[r] = v;
    }
    if (l31 == 0) {
#pragma unroll
      for (int r = 0; r < 16; ++r)
        lsh[wave][(r & 3) + 8 * (r >> 2) + 4 * lh] = lrun[r];
    }
    // same-wave LDS dep: compiler inserts lgkm wait
    float li = __builtin_amdgcn_rcpf(lsh[wave][l31]);
#pragma unroll
    for (int r = 0; r < 16; ++r) {
      int dr = (r & 3) + 8 * (r >> 2) + 4 * lh;
      AO[((size_t)b * NC + h * NDK + dr) * NL + i0 + l31] = f2b(o0[r] * li);
      AO[((size_t)b * NC + h * NDK + 32 + dr) * NL + i0 + l31] = f2b(o1[r] * li);
    }
  }
}

// ---- final projection GEMM (fp32 out) --------------------------------------
__global__ __launch_bounds__(256) void final_gemm_kernel(
    const unsigned short* __restrict__ AO, const unsigned short* __restrict__ W,
    const float* __restrict__ bias, float* __restrict__ out) {
  int b = blockIdx.z;
  __shared__ __attribute__((aligned(16))) unsigned short buf[16384];
  unsigned short* lA = buf;
  unsigned short* lB = buf + 8192;
  int m0 = blockIdx.y * 128, n0 = blockIdx.x * 128;
  float4v acc[4][4];
#pragma unroll
  for (int i = 0; i < 4; ++i)
#pragma unroll
    for (int j = 0; j < 4; ++j) acc[i][j] = (float4v){0.f, 0.f, 0.f, 0.f};
  gemm_core_bk64(AO + (size_t)b * 512 * 512, W, lA, lB, acc, m0, n0);
  int lane = threadIdx.x & 63, quad = lane >> 4, l15 = lane & 15;
  int wave = threadIdx.x >> 6, wr = wave >> 1, wc = wave & 1;
#pragma unroll
  for (int mt = 0; mt < 4; ++mt)
#pragma unroll
    for (int nt = 0; nt < 4; ++nt) {
      int n = n0 + wc * 64 + nt * 16 + l15;
      float bn = bias[n];
#pragma unroll
      for (int r = 0; r < 4; ++r) {
        int m = m0 + wr * 64 + mt * 16 + quad * 4 + r;
        out[((size_t)b * 512 + m) * 512 + n] = acc[mt][nt][r] + bn;
      }
    }
}

extern "C" void kernel_launch(void* const* d_in, const int* in_sizes, int n_in,
                              void* d_out, int out_size, void* d_ws, size_t ws_size,
                              hipStream_t stream) {
  (void)in_sizes; (void)n_in; (void)out_size; (void)ws_size;
  const float* query  = (const float*)d_in[0];
  const float* key    = (const float*)d_in[1];
  const float* value  = (const float*)d_in[2];
  const float* pos    = (const float*)d_in[3];
  const float* proj_w = (const float*)d_in[4];
  const float* proj_b = (const float*)d_in[5];
  const float* q_dw_w = (const float*)d_in[6];
  const float* q_dw_b = (const float*)d_in[7];
  const float* q_pw_w = (const float*)d_in[8];
  const float* q_pw_b = (const float*)d_in[9];
  const float* k_dw_w = (const float*)d_in[10];
  const float* k_dw_b = (const float*)d_in[11];
  const float* k_pw_w = (const float*)d_in[12];
  const float* k_pw_b = (const float*)d_in[13];
  const float* v_dw_w = (const float*)d_in[14];
  const float* v_dw_b = (const float*)d_in[15];
  const float* v_pw_w = (const float*)d_in[16];
  const float* v_pw_b = (const float*)d_in[17];

  char* ws = (char*)d_ws;
  const size_t WMAT = (size_t)512 * 512 * 2;     // 512 KB
  const size_t TEN  = (size_t)NB * NC * NL * 2;  // 16 MB
  unsigned short* wq  = (unsigned short*)(ws);
  unsigned short* wk  = (unsigned short*)(ws + WMAT);
  unsigned short* wv  = (unsigned short*)(ws + 2 * WMAT);
  unsigned short* wp  = (unsigned short*)(ws + 3 * WMAT);
  unsigned short* yq  = (unsigned short*)(ws + 4 * WMAT);
  unsigned short* yk  = (unsigned short*)(ws + 4 * WMAT + TEN);
  unsigned short* yv  = (unsigned short*)(ws + 4 * WMAT + 2 * TEN);
  unsigned short* qT  = (unsigned short*)(ws + 4 * WMAT + 3 * TEN);
  unsigned short* kT  = (unsigned short*)(ws + 4 * WMAT + 4 * TEN);
  unsigned short* vvb = (unsigned short*)(ws + 4 * WMAT + 5 * TEN);
  unsigned short* AO  = yq;  // yq fully consumed by pw(q) before attention writes

  // fused prep: dw-conv (z<96, with inline posconv for q,k) + cvt4 (z>=96)
  dw_kernel<<<dim3(8, 8, 112), 256, 0, stream>>>(
      query, key, value, pos,
      q_dw_w, k_dw_w, v_dw_w, q_dw_b, k_dw_b, v_dw_b,
      q_pw_w, k_pw_w, v_pw_w, proj_w, wq, wk, wv, wp,
      yq, yk, yv);

  pw_gemm_kernel<<<dim3(4, 4, 96), 256, 0, stream>>>(
      wq, wk, wv, yq, yk, yv, q_pw_b, k_pw_b, v_pw_b, qT, kT, vvb);

  attn_kernel<<<dim3(256), 256, 0, stream>>>(qT, kT, vvb, AO);

  final_gemm_kernel<<<dim3(4, 4, 32), 256, 0, stream>>>(AO, wp, proj_b, (float*)d_out);
}

// Round 9
// 257.903 us; speedup vs baseline: 1.0890x; 1.0446x over previous
//
#include <hip/hip_runtime.h>

typedef __attribute__((ext_vector_type(8))) short short8;
typedef __attribute__((ext_vector_type(4))) float float4v;
typedef __attribute__((ext_vector_type(16))) float float16v;
typedef __attribute__((ext_vector_type(4))) unsigned short ushort4v;

#define NB 32
#define NC 512
#define NL 512
#define NH 8
#define NDK 64

__device__ __forceinline__ unsigned short f2b(float f) {
  union { float f; unsigned int u; } v; v.f = f;
  unsigned int r = v.u + 0x7FFFu + ((v.u >> 16) & 1u);
  return (unsigned short)(r >> 16);
}

__device__ __forceinline__ void gld16(const void* g, void* l) {
  __builtin_amdgcn_global_load_lds(
      (const __attribute__((address_space(1))) unsigned int*)g,
      (__attribute__((address_space(3))) unsigned int*)l, 16, 0, 0);
}

__device__ __forceinline__ float4v bmfma(short8 a, short8 b, float4v c) {
  return __builtin_amdgcn_mfma_f32_16x16x32_bf16(a, b, c, 0, 0, 0);
}

// ---- fused prep: depthwise conv(7) with inline posconv for q,k; plus -------
// ---- fp32->bf16 weight conversion absorbed as extra z-slices ---------------
// dw core: c64 x l64 tile, one barrier, 6144 independent blocks.
// gld16 staging: LDS dest is WAVE-UNIFORM base + lane*16 (m104), so every
// wave is fully active -- all 1344 cells (incl. pad f4==20 and OOB halo)
// issue gld16 with a CLAMPED global address. Pad garbage never read; OOB
// halo garbage zeroed in registers (wave-uniform branches on edge blocks).
// Stride 84 == 20 mod 32 keeps the 64-lane b128 compute reads conflict-free.
__global__ __launch_bounds__(256) void dw_kernel(
    const float* __restrict__ q, const float* __restrict__ k, const float* __restrict__ v,
    const float* __restrict__ pos,
    const float* __restrict__ qw, const float* __restrict__ kw, const float* __restrict__ vw,
    const float* __restrict__ qb2, const float* __restrict__ kb2, const float* __restrict__ vb,
    const float* __restrict__ cq, const float* __restrict__ ck,
    const float* __restrict__ cv, const float* __restrict__ cp,
    unsigned short* __restrict__ wq, unsigned short* __restrict__ wk,
    unsigned short* __restrict__ wv, unsigned short* __restrict__ wp,
    unsigned short* __restrict__ yq, unsigned short* __restrict__ yk,
    unsigned short* __restrict__ yv) {
  int z = blockIdx.z;
  int tid = threadIdx.x;
  if (z >= 96) {
    // ---- cvt4 job: fp32 -> bf16, 4 matrices of 512x512 ----
    int idx = (z - 96) * 64 + blockIdx.y * 8 + blockIdx.x;
    int m = idx >> 8, blk = idx & 255;
    const float* src = (m == 0) ? cq : (m == 1) ? ck : (m == 2) ? cv : cp;
    unsigned short* dst = (m == 0) ? wq : (m == 1) ? wk : (m == 2) ? wv : wp;
    int i = (blk * 256 + tid) * 4;
    float4v vv = *(const float4v*)(src + i);
    ushort4v o;
    o.x = f2b(vv.x); o.y = f2b(vv.y); o.z = f2b(vv.z); o.w = f2b(vv.w);
    *(ushort4v*)(dst + i) = o;
    return;
  }
  int t = z >> 5, b = z & 31;
  const float* x   = (t == 0) ? q  : (t == 1) ? k  : v;
  const float* dww = (t == 0) ? qw : (t == 1) ? kw : vw;
  const float* dwb = (t == 0) ? qb2 : (t == 1) ? kb2 : vb;
  unsigned short* yT = (t == 0) ? yq : (t == 1) ? yk : yv;
  int c0 = blockIdx.y * 64, l0 = blockIdx.x * 64;
  __shared__ __attribute__((aligned(16))) float xs[64 * 84];
#pragma unroll
  for (int it = 0; it < 6; ++it) {
    int idx = tid + 256 * it;
    if (idx < 1344) {
      int row = idx / 21, f4 = idx - row * 21;
      int l = l0 - 8 + f4 * 4;
      int lc = l < 0 ? 0 : (l > NL - 4 ? NL - 4 : l);
      gld16(x + ((size_t)b * NC + c0 + row) * NL + lc, xs + idx * 4);
    }
  }
  int cl = tid & 63;
  int llb = (tid >> 6) * 16;
  int c = c0 + cl;
  // hoisted independent work: taps, bias, inline posconv (hides under staging)
  float wt[7];
#pragma unroll
  for (int tt = 0; tt < 7; ++tt) wt[tt] = dww[c * 7 + tt];
  float bias0 = dwb[c];
  float addv[16];
  if (t < 2) {
    // addv[i] = dwb[c] + sum_tt pos[l0+llb+i+tt-3, c] * wt[tt]
    float pv[22];
#pragma unroll
    for (int j = 0; j < 22; ++j) {
      int ll = l0 + llb - 3 + j;
      pv[j] = ((unsigned)ll < (unsigned)NL) ? pos[(size_t)ll * NC + c] : 0.f;
    }
#pragma unroll
    for (int i = 0; i < 16; ++i) {
      float acc = bias0;
#pragma unroll
      for (int tt = 0; tt < 7; ++tt) acc += pv[i + tt] * wt[tt];
      addv[i] = acc;
    }
  } else {
#pragma unroll
    for (int i = 0; i < 16; ++i) addv[i] = bias0;
  }
  __syncthreads();
  // per-thread window: w[j] = x[l0 + llb - 4 + j], j = 0..23
  float w[24];
  const float4v* xr = (const float4v*)(xs + cl * 84 + llb + 4);
#pragma unroll
  for (int j = 0; j < 6; ++j) {
    float4v t4 = xr[j];
    w[4 * j] = t4.x; w[4 * j + 1] = t4.y; w[4 * j + 2] = t4.z; w[4 * j + 3] = t4.w;
  }
  // zero the OOB taps (clamped-load garbage); wave-uniform branches.
  if (blockIdx.x == 0 && llb == 0) {
    w[0] = 0.f; w[1] = 0.f; w[2] = 0.f; w[3] = 0.f;
  } else if (blockIdx.x == 7 && llb == 48) {
    w[20] = 0.f; w[21] = 0.f; w[22] = 0.f; w[23] = 0.f;
  }
#pragma unroll
  for (int i = 0; i < 16; ++i) {
    float acc = addv[i];
#pragma unroll
    for (int tt = 0; tt < 7; ++tt) acc += w[i + 1 + tt] * wt[tt];
    yT[((size_t)b * NL + l0 + llb + i) * NC + c] = f2b(acc);
  }
}

// ---- 128x128 MFMA GEMM core, BK=64, global-XOR-swizzled staging ------------
__device__ __forceinline__ void gemm_core_bk64(
    const unsigned short* __restrict__ A, const unsigned short* __restrict__ B,
    unsigned short* lA, unsigned short* lB, float4v acc[4][4], int m0, int n0) {
  int tid = threadIdx.x;
  int lane = tid & 63, quad = lane >> 4, l15 = lane & 15;
  int wave = tid >> 6, wr = wave >> 1, wc = wave & 1;
  const unsigned short* gA[4];
  const unsigned short* gB[4];
  unsigned short* dA[4];
  unsigned short* dB[4];
#pragma unroll
  for (int i = 0; i < 4; ++i) {
    int cc = tid + 256 * i;
    int row = cc >> 3;
    int gc = (cc & 7) ^ (row & 7);
    gA[i] = A + (size_t)(m0 + row) * 512 + gc * 8;
    gB[i] = B + (size_t)(n0 + row) * 512 + gc * 8;
    dA[i] = lA + cc * 8;
    dB[i] = lB + cc * 8;
  }
  for (int k0 = 0; k0 < 512; k0 += 64) {
#pragma unroll
    for (int i = 0; i < 4; ++i) gld16(gA[i] + k0, dA[i]);
#pragma unroll
    for (int i = 0; i < 4; ++i) gld16(gB[i] + k0, dB[i]);
    __syncthreads();
#pragma unroll
    for (int ks = 0; ks < 2; ++ks) {
      int sw = (ks * 4 + quad) ^ (l15 & 7);
      short8 af[4], bf[4];
#pragma unroll
      for (int mt = 0; mt < 4; ++mt)
        af[mt] = *(const short8*)(lA + (wr * 64 + mt * 16 + l15) * 64 + sw * 8);
#pragma unroll
      for (int nt = 0; nt < 4; ++nt)
        bf[nt] = *(const short8*)(lB + (wc * 64 + nt * 16 + l15) * 64 + sw * 8);
#pragma unroll
      for (int mt = 0; mt < 4; ++mt)
#pragma unroll
        for (int nt = 0; nt < 4; ++nt)
          acc[mt][nt] = bmfma(af[mt], bf[nt], acc[mt][nt]);
    }
    __syncthreads();
  }
}

// ---- fused pointwise GEMMs for q,k,v ---------------------------------------
// q output is pre-scaled by 0.125*log2(e) so attention can use exp2 directly.
// q/k epilogue: LDS transpose in [n][m] layout, XOR-swizzled m-index.
// v epilogue: LDS transpose in [m][n] layout, XOR-swizzled n-index ->
// short8 n-contiguous stores.
__global__ __launch_bounds__(256) void pw_gemm_kernel(
    const unsigned short* __restrict__ wqm, const unsigned short* __restrict__ wkm,
    const unsigned short* __restrict__ wvm,
    const unsigned short* __restrict__ yq, const unsigned short* __restrict__ yk,
    const unsigned short* __restrict__ yv,
    const float* __restrict__ qb, const float* __restrict__ kb, const float* __restrict__ vb,
    unsigned short* __restrict__ qT, unsigned short* __restrict__ kT,
    unsigned short* __restrict__ vvo) {
  int z = blockIdx.z, t = z >> 5, b = z & 31;
  const unsigned short* W = (t == 0) ? wqm : (t == 1) ? wkm : wvm;
  const unsigned short* Y = ((t == 0) ? yq : (t == 1) ? yk : yv) + (size_t)b * NL * NC;
  const float* bias = (t == 0) ? qb : (t == 1) ? kb : vb;
  unsigned short* out = (t == 0) ? qT : (t == 1) ? kT : vvo;
  float oscale = (t == 0) ? 0.18033688011112042f : 1.0f;  // 0.125*log2(e) folded into q
  __shared__ __attribute__((aligned(16))) unsigned short buf[16384];
  unsigned short* lA = buf;
  unsigned short* lB = buf + 8192;
  int m0 = blockIdx.y * 128, n0 = blockIdx.x * 128;
  float4v acc[4][4];
#pragma unroll
  for (int i = 0; i < 4; ++i)
#pragma unroll
    for (int j = 0; j < 4; ++j) acc[i][j] = (float4v){0.f, 0.f, 0.f, 0.f};
  gemm_core_bk64(W, Y, lA, lB, acc, m0, n0);
  int tid = threadIdx.x;
  int lane = tid & 63, quad = lane >> 4, l15 = lane & 15;
  int wave = tid >> 6, wr = wave >> 1, wc = wave & 1;
  if (t < 2) {
#pragma unroll
    for (int mt = 0; mt < 4; ++mt) {
      int mloc = wr * 64 + mt * 16 + quad * 4;
#pragma unroll
      for (int nt = 0; nt < 4; ++nt) {
        int nloc = wc * 64 + nt * 16 + l15;
        int sx = (nloc & 7) << 3;
#pragma unroll
        for (int r = 0; r < 4; ++r) {
          int ml = mloc + r;
          buf[(ml >> 6) * 8192 + nloc * 64 + ((ml & 63) ^ sx)] =
              f2b((acc[mt][nt][r] + bias[m0 + ml]) * oscale);
        }
      }
    }
    __syncthreads();
#pragma unroll
    for (int it = 0; it < 8; ++it) {
      int cc = tid + it * 256;
      int hloc = cc >> 10, l = (cc >> 3) & 127, dc = cc & 7;
      short8 vd = *(const short8*)(buf + hloc * 8192 + l * 64 + ((dc ^ (l & 7)) << 3));
      *(short8*)(out + (((size_t)b * NH + (m0 >> 6) + hloc) * NL + n0 + l) * NDK + dc * 8) = vd;
    }
  } else {
#pragma unroll
    for (int mt = 0; mt < 4; ++mt) {
      int mloc = wr * 64 + mt * 16 + quad * 4;
#pragma unroll
      for (int nt = 0; nt < 4; ++nt) {
        int nloc = wc * 64 + nt * 16 + l15;
#pragma unroll
        for (int r = 0; r < 4; ++r) {
          int ml = mloc + r;
          buf[(ml >> 6) * 8192 + (ml & 63) * 128 + (nloc ^ ((ml & 7) << 3))] =
              f2b(acc[mt][nt][r] + bias[m0 + ml]);
        }
      }
    }
    __syncthreads();
#pragma unroll
    for (int it = 0; it < 8; ++it) {
      int cc = tid + it * 256;
      int half = cc >> 10, m = (cc >> 4) & 63, dc = cc & 15;
      short8 vd = *(const short8*)(buf + half * 8192 + m * 128 + ((dc ^ (m & 7)) << 3));
      *(short8*)(out + ((size_t)b * NC + m0 + half * 64 + m) * NL + n0 + dc * 8) = vd;
    }
  }
}

// ---- persistent attention, swapped-QK^T, P fully in-register ---------------
// R8 profile: 1 wave/SIMD (148KB LDS, 4-wave block) -> every dep chain
// exposed; MfmaUtil 10%, occ 10%. R9: compute S^T = mfma(K,Q) so each lane
// owns one i-COLUMN; P packs to bf16 in-register (f2b pairs), halves exchange
// via shfl_xor(32), PV B-fragment built by per-half select -> NO P LDS
// buffer (kills its bank conflicts + same-wave store/load chain). Row sums:
// 16 lane-local adds + one shfl_xor(32) (replaces 80-shuffle butterfly+lsh).
// LDS = Kt+Vt = 128KB -> 512-thread 8-wave block fits -> 2 waves/SIMD.
__global__ __launch_bounds__(512, 1) void attn_kernel(
    const unsigned short* __restrict__ qT,  // (B,H,L,DK)
    const unsigned short* __restrict__ kT,  // (B,H,L,DK)
    const unsigned short* __restrict__ vv,  // (B,C,L)
    unsigned short* __restrict__ AO) {      // (B,C,L)
  int bh = blockIdx.x, b = bh >> 3, h = bh & 7;
  int tid = threadIdx.x, lane = tid & 63;
  int l31 = lane & 31, lh = lane >> 5;
  int wave = tid >> 6;
  __shared__ __attribute__((aligned(16))) unsigned short Kt[512 * 64];  // [j][d] swz
  __shared__ __attribute__((aligned(16))) unsigned short Vt[64 * 512];  // [d][j] swz
  const unsigned short* qh = qT + (size_t)bh * NL * NDK;
  const unsigned short* kh = kT + (size_t)bh * NL * NDK;
  const unsigned short* vh = vv + ((size_t)b * NC + h * NDK) * NL;

  // one-time stage of all K and V (swizzle realized on the global side)
#pragma unroll
  for (int ii = 0; ii < 8; ++ii) {
    int cc = tid + 512 * ii;
    int row = cc >> 3, c = (cc & 7) ^ (row & 7);
    gld16(kh + (size_t)row * NDK + c * 8, &Kt[cc * 8]);
  }
#pragma unroll
  for (int ii = 0; ii < 8; ++ii) {
    int cc = tid + 512 * ii;
    int d = cc >> 6, pc = cc & 63;
    int c = (pc & ~7) | ((pc & 7) ^ (d & 7));
    gld16(vh + (size_t)d * NL + c * 8, &Vt[cc * 8]);
  }
  __syncthreads();  // only barrier in the kernel

#pragma unroll
  for (int iset = 0; iset < 2; ++iset) {
    int i0 = wave * 64 + iset * 32;
    // Q as B-operand: n = i = i0 + l31, k = d = s*16 + lh*8 + e
    short8 a[4];
#pragma unroll
    for (int s = 0; s < 4; ++s)
      a[s] = *(const short8*)(qh + (size_t)(i0 + l31) * NDK + s * 16 + lh * 8);
    float16v o0, o1;
#pragma unroll
    for (int r = 0; r < 16; ++r) { o0[r] = 0.f; o1[r] = 0.f; }
    float lsum = 0.f;

    for (int jb = 0; jb < 16; ++jb) {
      // S^T = mfma(K, Q): D[m=j][n=i]; lane owns column i, regs span 32 j
      float16v sacc;
#pragma unroll
      for (int r = 0; r < 16; ++r) sacc[r] = 0.f;
#pragma unroll
      for (int s = 0; s < 4; ++s) {
        int cslot = (s * 2 + lh) ^ (l31 & 7);
        short8 kbf = *(const short8*)(&Kt[(size_t)(jb * 32 + l31) * 64 + cslot * 8]);
        sacc = __builtin_amdgcn_mfma_f32_32x32x16_bf16(kbf, a[s], sacc, 0, 0, 0);
      }
      // p = exp2(s); per-lane row-sum partial (all 16 regs belong to col i)
      float p[16];
#pragma unroll
      for (int r = 0; r < 16; ++r) {
        p[r] = __builtin_amdgcn_exp2f(sacc[r]);
        lsum += p[r];
      }
      // pack to bf16 pairs; reg r holds j_local = (r&3)+8*(r>>2)+4*lh
      unsigned int c0 = (unsigned)f2b(p[0])  | ((unsigned)f2b(p[1])  << 16);  // j {0,1}+4lh
      unsigned int c1 = (unsigned)f2b(p[2])  | ((unsigned)f2b(p[3])  << 16);  // j {2,3}+4lh
      unsigned int c2 = (unsigned)f2b(p[4])  | ((unsigned)f2b(p[5])  << 16);  // j {8,9}+4lh
      unsigned int c3 = (unsigned)f2b(p[6])  | ((unsigned)f2b(p[7])  << 16);  // j {10,11}+4lh
      unsigned int c4 = (unsigned)f2b(p[8])  | ((unsigned)f2b(p[9])  << 16);  // j {16,17}+4lh
      unsigned int c5 = (unsigned)f2b(p[10]) | ((unsigned)f2b(p[11]) << 16);  // j {18,19}+4lh
      unsigned int c6 = (unsigned)f2b(p[12]) | ((unsigned)f2b(p[13]) << 16);  // j {24,25}+4lh
      unsigned int c7 = (unsigned)f2b(p[14]) | ((unsigned)f2b(p[15]) << 16);  // j {26,27}+4lh
      unsigned int q0 = __shfl_xor(c0, 32);
      unsigned int q1 = __shfl_xor(c1, 32);
      unsigned int q2 = __shfl_xor(c2, 32);
      unsigned int q3 = __shfl_xor(c3, 32);
      unsigned int q4 = __shfl_xor(c4, 32);
      unsigned int q5 = __shfl_xor(c5, 32);
      unsigned int q6 = __shfl_xor(c6, 32);
      unsigned int q7 = __shfl_xor(c7, 32);
      // B-fragment for PV: lane needs k = j = js*16 + lh*8 + e
      union { unsigned int u[4]; short8 s8; } f0, f1;
      f0.u[0] = lh ? q2 : c0;  f0.u[1] = lh ? q3 : c1;
      f0.u[2] = lh ? c2 : q0;  f0.u[3] = lh ? c3 : q1;
      f1.u[0] = lh ? q6 : c4;  f1.u[1] = lh ? q7 : c5;
      f1.u[2] = lh ? c6 : q4;  f1.u[3] = lh ? c7 : q5;
      // O += V P^T : A = V[d][j] from Vt, B = frag (register-resident)
#pragma unroll
      for (int js = 0; js < 2; ++js) {
        int g = jb * 4 + js * 2 + lh;
        int vc = (g & ~7) | ((g & 7) ^ (l31 & 7));
        short8 av0 = *(const short8*)(&Vt[(size_t)l31 * 512 + vc * 8]);
        short8 av1 = *(const short8*)(&Vt[(size_t)(32 + l31) * 512 + vc * 8]);
        short8 fb = js ? f1.s8 : f0.s8;
        o0 = __builtin_amdgcn_mfma_f32_32x32x16_bf16(av0, fb, o0, 0, 0, 0);
        o1 = __builtin_amdgcn_mfma_f32_32x32x16_bf16(av1, fb, o1, 0, 0, 0);
      }
    }
    // full row sum for column i: own half + partner half
    float tot = lsum + __shfl_xor(lsum, 32);
    float li = __builtin_amdgcn_rcpf(tot);
#pragma unroll
    for (int r = 0; r < 16; ++r) {
      int dr = (r & 3) + 8 * (r >> 2) + 4 * lh;
      AO[((size_t)b * NC + h * NDK + dr) * NL + i0 + l31] = f2b(o0[r] * li);
      AO[((size_t)b * NC + h * NDK + 32 + dr) * NL + i0 + l31] = f2b(o1[r] * li);
    }
  }
}

// ---- final projection GEMM (fp32 out) --------------------------------------
__global__ __launch_bounds__(256) void final_gemm_kernel(
    const unsigned short* __restrict__ AO, const unsigned short* __restrict__ W,
    const float* __restrict__ bias, float* __restrict__ out) {
  int b = blockIdx.z;
  __shared__ __attribute__((aligned(16))) unsigned short buf[16384];
  unsigned short* lA = buf;
  unsigned short* lB = buf + 8192;
  int m0 = blockIdx.y * 128, n0 = blockIdx.x * 128;
  float4v acc[4][4];
#pragma unroll
  for (int i = 0; i < 4; ++i)
#pragma unroll
    for (int j = 0; j < 4; ++j) acc[i][j] = (float4v){0.f, 0.f, 0.f, 0.f};
  gemm_core_bk64(AO + (size_t)b * 512 * 512, W, lA, lB, acc, m0, n0);
  int lane = threadIdx.x & 63, quad = lane >> 4, l15 = lane & 15;
  int wave = threadIdx.x >> 6, wr = wave >> 1, wc = wave & 1;
#pragma unroll
  for (int mt = 0; mt < 4; ++mt)
#pragma unroll
    for (int nt = 0; nt < 4; ++nt) {
      int n = n0 + wc * 64 + nt * 16 + l15;
      float bn = bias[n];
#pragma unroll
      for (int r = 0; r < 4; ++r) {
        int m = m0 + wr * 64 + mt * 16 + quad * 4 + r;
        out[((size_t)b * 512 + m) * 512 + n] = acc[mt][nt][r] + bn;
      }
    }
}

extern "C" void kernel_launch(void* const* d_in, const int* in_sizes, int n_in,
                              void* d_out, int out_size, void* d_ws, size_t ws_size,
                              hipStream_t stream) {
  (void)in_sizes; (void)n_in; (void)out_size; (void)ws_size;
  const float* query  = (const float*)d_in[0];
  const float* key    = (const float*)d_in[1];
  const float* value  = (const float*)d_in[2];
  const float* pos    = (const float*)d_in[3];
  const float* proj_w = (const float*)d_in[4];
  const float* proj_b = (const float*)d_in[5];
  const float* q_dw_w = (const float*)d_in[6];
  const float* q_dw_b = (const float*)d_in[7];
  const float* q_pw_w = (const float*)d_in[8];
  const float* q_pw_b = (const float*)d_in[9];
  const float* k_dw_w = (const float*)d_in[10];
  const float* k_dw_b = (const float*)d_in[11];
  const float* k_pw_w = (const float*)d_in[12];
  const float* k_pw_b = (const float*)d_in[13];
  const float* v_dw_w = (const float*)d_in[14];
  const float* v_dw_b = (const float*)d_in[15];
  const float* v_pw_w = (const float*)d_in[16];
  const float* v_pw_b = (const float*)d_in[17];

  char* ws = (char*)d_ws;
  const size_t WMAT = (size_t)512 * 512 * 2;     // 512 KB
  const size_t TEN  = (size_t)NB * NC * NL * 2;  // 16 MB
  unsigned short* wq  = (unsigned short*)(ws);
  unsigned short* wk  = (unsigned short*)(ws + WMAT);
  unsigned short* wv  = (unsigned short*)(ws + 2 * WMAT);
  unsigned short* wp  = (unsigned short*)(ws + 3 * WMAT);
  unsigned short* yq  = (unsigned short*)(ws + 4 * WMAT);
  unsigned short* yk  = (unsigned short*)(ws + 4 * WMAT + TEN);
  unsigned short* yv  = (unsigned short*)(ws + 4 * WMAT + 2 * TEN);
  unsigned short* qT  = (unsigned short*)(ws + 4 * WMAT + 3 * TEN);
  unsigned short* kT  = (unsigned short*)(ws + 4 * WMAT + 4 * TEN);
  unsigned short* vvb = (unsigned short*)(ws + 4 * WMAT + 5 * TEN);
  unsigned short* AO  = yq;  // yq fully consumed by pw(q) before attention writes

  // fused prep: dw-conv (z<96, with inline posconv for q,k) + cvt4 (z>=96)
  dw_kernel<<<dim3(8, 8, 112), 256, 0, stream>>>(
      query, key, value, pos,
      q_dw_w, k_dw_w, v_dw_w, q_dw_b, k_dw_b, v_dw_b,
      q_pw_w, k_pw_w, v_pw_w, proj_w, wq, wk, wv, wp,
      yq, yk, yv);

  pw_gemm_kernel<<<dim3(4, 4, 96), 256, 0, stream>>>(
      wq, wk, wv, yq, yk, yv, q_pw_b, k_pw_b, v_pw_b, qT, kT, vvb);

  attn_kernel<<<dim3(256), 512, 0, stream>>>(qT, kT, vvb, AO);

  final_gemm_kernel<<<dim3(4, 4, 32), 256, 0, stream>>>(AO, wp, proj_b, (float*)d_out);
}